// Round 1
// baseline (440.653 us; speedup 1.0000x reference)
//
#include <hip/hip_runtime.h>

// SpatialEncoding: out[N,N] = 0; out[src[e], dst[e]] = b[clip(path_len[e],1,5)-1]
// with numpy semantics: for duplicate (src,dst), the LAST edge index wins.
// Deterministic via atomicMax on key = ((e+1)<<3) | bias_idx, then decode.

constexpr int MAXPD = 5;

__global__ void zero_keys_kernel(unsigned int* __restrict__ out, long long n) {
    long long n4 = n >> 2;
    long long i = (long long)blockIdx.x * blockDim.x + threadIdx.x;
    long long stride = (long long)gridDim.x * blockDim.x;
    uint4* p = reinterpret_cast<uint4*>(out);
    for (long long j = i; j < n4; j += stride) {
        p[j] = make_uint4(0u, 0u, 0u, 0u);
    }
    // tail (n not multiple of 4)
    long long base = n4 << 2;
    for (long long j = base + i; j < n; j += stride) {
        out[j] = 0u;
    }
}

__global__ void scatter_keys_kernel(const int* __restrict__ src,
                                    const int* __restrict__ dst,
                                    const int* __restrict__ plen,
                                    unsigned int* __restrict__ keys,
                                    int E, int N) {
    int i = blockIdx.x * blockDim.x + threadIdx.x;
    int stride = gridDim.x * blockDim.x;
    for (int e = i; e < E; e += stride) {
        int s = src[e];
        int d = dst[e];
        int pl = plen[e];
        // bias index = clip(pl, 1, MAXPD) - 1  ->  [0, MAXPD-1]
        int bi = pl < 1 ? 0 : (pl > MAXPD ? (MAXPD - 1) : (pl - 1));
        unsigned int key = (((unsigned int)e + 1u) << 3) | (unsigned int)bi;
        atomicMax(keys + (long long)s * (long long)N + d, key);
    }
}

__global__ void decode_keys_kernel(unsigned int* __restrict__ data, long long n,
                                   const float* __restrict__ b) {
    __shared__ float sb[8];
    if (threadIdx.x < 8) {
        sb[threadIdx.x] = (threadIdx.x < MAXPD) ? b[threadIdx.x] : 0.0f;
    }
    __syncthreads();

    long long n4 = n >> 2;
    long long i = (long long)blockIdx.x * blockDim.x + threadIdx.x;
    long long stride = (long long)gridDim.x * blockDim.x;
    uint4* p = reinterpret_cast<uint4*>(data);
    float4* f = reinterpret_cast<float4*>(data);
    for (long long j = i; j < n4; j += stride) {
        uint4 k = p[j];
        float4 v;
        v.x = k.x ? sb[k.x & 7u] : 0.0f;
        v.y = k.y ? sb[k.y & 7u] : 0.0f;
        v.z = k.z ? sb[k.z & 7u] : 0.0f;
        v.w = k.w ? sb[k.w & 7u] : 0.0f;
        f[j] = v;
    }
    long long base = n4 << 2;
    float* fo = reinterpret_cast<float*>(data);
    for (long long j = base + i; j < n; j += stride) {
        unsigned int k = data[j];
        fo[j] = k ? sb[k & 7u] : 0.0f;
    }
}

extern "C" void kernel_launch(void* const* d_in, const int* in_sizes, int n_in,
                              void* d_out, int out_size, void* d_ws, size_t ws_size,
                              hipStream_t stream) {
    // inputs: x [N,128] f32 (unused values), src [E] i32, dst [E] i32,
    //         path_len [E] i32, b [5] f32
    const int* src  = (const int*)d_in[1];
    const int* dst  = (const int*)d_in[2];
    const int* plen = (const int*)d_in[3];
    const float* b  = (const float*)d_in[4];

    int N = in_sizes[0] / 128;      // 8192
    int E = in_sizes[1];            // 8,000,000
    long long n = (long long)out_size;  // N*N

    unsigned int* keys = (unsigned int*)d_out;

    const int BLK = 256;
    // memory-bound: cap grid ~2048 blocks, grid-stride the rest
    int grid_zero = (int)min((n / 4 + BLK - 1) / BLK, (long long)2048);
    int grid_scat = min((E + BLK - 1) / BLK, 2048);
    int grid_dec  = grid_zero;

    zero_keys_kernel<<<grid_zero, BLK, 0, stream>>>(keys, n);
    scatter_keys_kernel<<<grid_scat, BLK, 0, stream>>>(src, dst, plen, keys, E, N);
    decode_keys_kernel<<<grid_dec, BLK, 0, stream>>>(keys, n, b);
}